// Round 10
// baseline (155.788 us; speedup 1.0000x reference)
//
#include <hip/hip_runtime.h>

// Problem constants (fixed by setup_inputs)
constexpr int B = 4, N = 2048, I = 256, H = 4, D = 64, E = 256; // E = H*D
constexpr float LOG2E = 1.44269504088896340736f;

typedef __bf16 bf16x8 __attribute__((ext_vector_type(8)));
typedef float f32x4 __attribute__((ext_vector_type(4)));
typedef unsigned short us8 __attribute__((ext_vector_type(8)));

__device__ __forceinline__ unsigned short f2bf(float f) {
    unsigned u = __builtin_bit_cast(unsigned, f);
    u = (u + 0x7FFFu + ((u >> 16) & 1u)) >> 16;  // RNE
    return (unsigned short)u;
}
__device__ __forceinline__ float bf2f(unsigned short s) {
    return __builtin_bit_cast(float, (unsigned)s << 16);
}

// ---------------- Kernel 0: pack adjacency to bitmask, Abits[b][j/32][i] ----------------
__global__ __launch_bounds__(256) void k_pack(const int* __restrict__ A,
                                              unsigned int* __restrict__ Abits) {
    int w = blockIdx.x * 4 + (threadIdx.x >> 6); // row id = b*N + i
    int l = threadIdx.x & 63;
    int b = w >> 11;
    int i = w & 2047;
    const int* Arow = A + (size_t)w * N;
    unsigned int* dst = Abits + (size_t)b * 64 * 2048 + i;
    #pragma unroll 4
    for (int it = 0; it < N / 64; ++it) { // 32
        int a = Arow[it * 64 + l];
        unsigned long long m = __ballot(a > 0);
        if (l == 0) {
            dst[(size_t)(it * 2) * 2048]     = (unsigned int)m;
            dst[(size_t)(it * 2 + 1) * 2048] = (unsigned int)(m >> 32);
        }
    }
}

// ---------------- Kernel 0b: Wo -> bf16 hi/lo B-fragment order ----------------
// WoF us8 idx (et*8+ks)*64+l : elem e = Wo[et*16+(l&15)][ks*32+(l>>4)*8+e]; lo at +8192
__global__ __launch_bounds__(256) void k_wof(const float* __restrict__ Wo,
                                             unsigned short* __restrict__ WoF) {
    int gid = blockIdx.x * 256 + threadIdx.x;  // 8192
    int l = gid & 63, ks = (gid >> 6) & 7, et = gid >> 9;
    int row = et * 16 + (l & 15);
    int col = ks * 32 + (l >> 4) * 8;
    const float* src = Wo + (size_t)row * E + col;
    us8 hi, lo;
    #pragma unroll
    for (int e = 0; e < 8; ++e) {
        float v = src[e];
        unsigned short hb = f2bf(v);
        hi[e] = hb;
        lo[e] = f2bf(v - bf2f(hb));
    }
    ((us8*)WoF)[gid] = hi;
    ((us8*)WoF)[8192 + gid] = lo;
}

// ---------------- Kernel 1: projection + H1/H2i (log2-scaled) + HpF (B-fragment order) ----------------
constexpr int NT = 8; // nodes per block

__global__ __launch_bounds__(256) void k_proj(const float* __restrict__ X,
                                              const float* __restrict__ W,
                                              const float* __restrict__ a,
                                              unsigned short* __restrict__ HpF,
                                              float* __restrict__ H1,
                                              float* __restrict__ H2i) {
    int blk = blockIdx.x;
    int b = blk / (N / NT);
    int n0 = (blk % (N / NT)) * NT;
    int t = threadIdx.x;
    int h = t >> 6, d = t & 63;

    __shared__ float Xs[NT][I]; // 8 KB

    const float4* Xr = (const float4*)(X + ((size_t)b * N + n0) * I);
    #pragma unroll
    for (int k = 0; k < (NT * I / 4) / 256; ++k) { // 2 iters
        int v = t + 256 * k;
        ((float4*)&Xs[0][0])[v] = Xr[v];
    }
    __syncthreads();

    float acc[NT];
    #pragma unroll
    for (int nn = 0; nn < NT; ++nn) acc[nn] = 0.f;

    const float* Wp = W + (size_t)h * I * D + d;
    #pragma unroll 2
    for (int i4 = 0; i4 < I; i4 += 4) {
        float w0 = Wp[(size_t)(i4 + 0) * D];
        float w1 = Wp[(size_t)(i4 + 1) * D];
        float w2 = Wp[(size_t)(i4 + 2) * D];
        float w3 = Wp[(size_t)(i4 + 3) * D];
        #pragma unroll
        for (int nn = 0; nn < NT; ++nn) {
            float4 x = *(const float4*)&Xs[nn][i4];
            acc[nn] += x.x * w0 + x.y * w1 + x.z * w2 + x.w * w3;
        }
    }

    float a1 = a[h * (2 * D) + d];
    float a2 = a[h * (2 * D) + D + d];

    #pragma unroll
    for (int nn = 0; nn < NT; ++nn) {
        float v1 = acc[nn] * a1;
        float v2 = acc[nn] * a2;
        #pragma unroll
        for (int off = 32; off > 0; off >>= 1) {
            v1 += __shfl_down(v1, off, 64);
            v2 += __shfl_down(v2, off, 64);
        }
        if (d == 0) {
            H1[(size_t)(b * H + h) * N + (n0 + nn)] = v1 * LOG2E;
            H2i[((size_t)b * N + n0 + nn) * H + h] = v2 * LOG2E;
        }
    }

    // fragment-order bf16 store (one contiguous us8 per thread)
    us8 o;
    #pragma unroll
    for (int nn = 0; nn < NT; ++nn) o[nn] = f2bf(acc[nn]);
    int jblk = n0 >> 5, g = (n0 >> 3) & 3;
    int lane = (d & 15) + 16 * g, ntt = d >> 4;
    ((us8*)HpF)[(((size_t)(b * H + h) * 64 + jblk) * 4 + ntt) * 64 + lane] = o;
}

// ---------------- Kernel 2: barrier-free per-wave head-softmax + MFMA aggregation ----------------
// 2048 blocks x 4 waves = 8192 independent waves. Block = (jq, b, i-tile of 16); wave
// wv covers j in [jq*512 + wv*128, +128) -> 4 steps of 32 j. Lane l owns A-frag slots
// (row=l&15, k=(l>>4)*8+e); 4-head softmax once per pair in regs; mask from bit-words
// (all 4 loaded upfront); B-frags = coalesced 1KB loads from HpF. End-of-kernel
// 4-wave LDS reduce -> one bf16 chunk per block (4 jq partials globally).
constexpr int JQ = 4;               // j-quarter splits (chunks)
constexpr int NSTEP = 4;            // 32-j steps per wave
constexpr int CH = 4096;            // u16 per (jq,b,it) chunk: 64 q-slots x 64 lanes

__global__ __launch_bounds__(256) void k_agg(const unsigned int* __restrict__ Abits,
                                             const float* __restrict__ H1,
                                             const float* __restrict__ H2i,
                                             const unsigned short* __restrict__ HpF,
                                             unsigned short* __restrict__ part) {
    __shared__ unsigned short red[4][CH]; // 32 KB

    int bid = blockIdx.x;
    int it = bid & 127;
    int b  = (bid >> 7) & 3;
    int jq = bid >> 9;           // 0..3
    int t = threadIdx.x;
    int wv = t >> 6, l = t & 63;
    int i0 = it * 16;
    int jb = jq * 512 + wv * 128;
    int jt0 = jb >> 5;           // first 32-j tile index
    int row = l & 15;  // A-frag row / B-frag col
    int kg  = l >> 4;  // k-chunk: k = kg*8 + e

    float h1v[H];
    #pragma unroll
    for (int h = 0; h < H; ++h) h1v[h] = H1[(size_t)(b * H + h) * N + i0 + row];

    f32x4 acc[H][4] = {}; // [head][d-tile]

    const unsigned int* Abp = Abits + (size_t)b * 64 * 2048 + i0 + row; // + jt*2048
    const float4* H2r = (const float4*)(H2i + ((size_t)b * N + jb + kg * 8) * H);
    const us8* Hf = (const us8*)HpF + ((size_t)(b * H) * 64 + jt0) * 256 + l;

    // all 4 mask words upfront
    unsigned int aw[NSTEP];
    #pragma unroll
    for (int s = 0; s < NSTEP; ++s) aw[s] = Abp[(size_t)(jt0 + s) * 2048];

    #pragma unroll
    for (int s = 0; s < NSTEP; ++s) {
        // ---- softmax for 8 pairs, all 4 heads; bit-test mask, one float4 H2/pair ----
        bf16x8 af[H];
        #pragma unroll
        for (int e = 0; e < 8; ++e) {
            bool on = (aw[s] >> (kg * 8 + e)) & 1u;
            float4 h2 = H2r[s * 32 + e]; // heads 0..3 of pair j = jb+kg*8+s*32+e
            float v0 = h1v[0] + h2.x;
            float v1 = h1v[1] + h2.y;
            float v2 = h1v[2] + h2.z;
            float v3 = h1v[3] + h2.w;
            // leaky-relu in log2 domain; mask score to 0 (exp2(0)=1 -> w=0.25 exact)
            float s0 = on ? fmaxf(v0, 0.2f * v0) : 0.f;
            float s1 = on ? fmaxf(v1, 0.2f * v1) : 0.f;
            float s2 = on ? fmaxf(v2, 0.2f * v2) : 0.f;
            float s3 = on ? fmaxf(v3, 0.2f * v3) : 0.f;
            float e0 = exp2f(s0);
            float e1 = exp2f(s1);
            float e2 = exp2f(s2);
            float e3 = exp2f(s3);
            float zi = __builtin_amdgcn_rcpf(e0 + e1 + e2 + e3);
            af[0][e] = (__bf16)(e0 * zi);
            af[1][e] = (__bf16)(e1 * zi);
            af[2][e] = (__bf16)(e2 * zi);
            af[3][e] = (__bf16)(e3 * zi);
        }

        // ---- MFMA: 4 heads x 4 d-tiles; B-frag = coalesced 1KB load ----
        #pragma unroll
        for (int h = 0; h < H; ++h) {
            #pragma unroll
            for (int nt = 0; nt < 4; ++nt) {
                bf16x8 bfr = __builtin_bit_cast(bf16x8, Hf[(size_t)h * 64 * 256 + s * 256 + nt * 64]);
                acc[h][nt] = __builtin_amdgcn_mfma_f32_16x16x32_bf16(af[h], bfr, acc[h][nt], 0, 0, 0);
            }
        }
    }

    // ---- end-of-kernel reduce: each wave dumps bf16 to its LDS slot; sum 4 slots ----
    #pragma unroll
    for (int h = 0; h < H; ++h)
        #pragma unroll
        for (int nt = 0; nt < 4; ++nt)
            #pragma unroll
            for (int r = 0; r < 4; ++r)
                red[wv][(((h * 4 + nt) * 4 + r)) * 64 + l] = f2bf(acc[h][nt][r]);
    __syncthreads();

    unsigned short* chunk = part + (((size_t)jq * B + b) * 128 + it) * CH;
    #pragma unroll
    for (int k = 0; k < CH / 256; ++k) { // 16
        int idx = t + 256 * k;
        float s = bf2f(red[0][idx]) + bf2f(red[1][idx]) + bf2f(red[2][idx]) + bf2f(red[3][idx]);
        chunk[idx] = f2bf(s);
    }
}

// ---------------- Kernel 3: MFMA out-GEMM, no LDS, no barriers ----------------
// Chunk layout: for (n' = h*512 + it*4 + kg, k = r*64 + nt*16 + rw):
//   chunk(jq,b,it)[ ((h*4+nt)*4+r)*64 + kg*16 + rw ]
// A-frag (row m=l&15 -> it=it0+(m>>2), kg=m&3; k=ks*32+(l>>4)*8+e) = contiguous us8.
// B-frag from WoF (hi+lo pair, 2 MFMAs -> Wo exact to fp32).
__global__ __launch_bounds__(256) void k_out(const unsigned short* __restrict__ part,
                                             const unsigned short* __restrict__ WoF,
                                             const float* __restrict__ bo,
                                             float* __restrict__ out) {
    int bid = blockIdx.x;           // ((b*32)+itg)*2 + eh
    int eh  = bid & 1;
    int itg = (bid >> 1) & 31;
    int b   = bid >> 6;
    int t = threadIdx.x;
    int h = t >> 6, l = t & 63;
    int it0 = itg * 4;
    int m = l & 15;                 // A-row within 16-row tile
    int it = it0 + (m >> 2), kg = m & 3;
    int kh = l >> 4;

    const unsigned short* cb = part + ((size_t)b * 128 + it) * CH; // + jq*B*128*CH
    const us8* wf = (const us8*)WoF;
    constexpr size_t JSTRIDE = (size_t)B * 128 * CH;

    f32x4 acc[8] = {};

    #pragma unroll
    for (int ks = 0; ks < 8; ++ks) {
        int k0 = ks * 32 + kh * 8;
        int nt = (k0 >> 4) & 3, r = k0 >> 6, rw0 = k0 & 15;
        int cidx = ((h * 4 + nt) * 4 + r) * 64 + kg * 16 + rw0;
        float s8[8] = {0.f, 0.f, 0.f, 0.f, 0.f, 0.f, 0.f, 0.f};
        #pragma unroll
        for (int jq = 0; jq < JQ; ++jq) {
            us8 p = *(const us8*)(cb + jq * JSTRIDE + cidx);
            #pragma unroll
            for (int e = 0; e < 8; ++e) s8[e] += bf2f(p[e]);
        }
        bf16x8 af;
        #pragma unroll
        for (int e = 0; e < 8; ++e) af[e] = (__bf16)s8[e];

        #pragma unroll
        for (int etl = 0; etl < 8; ++etl) {
            int et = eh * 8 + etl;
            bf16x8 bh = __builtin_bit_cast(bf16x8, wf[(size_t)(et * 8 + ks) * 64 + l]);
            bf16x8 bl = __builtin_bit_cast(bf16x8, wf[8192 + (size_t)(et * 8 + ks) * 64 + l]);
            acc[etl] = __builtin_amdgcn_mfma_f32_16x16x32_bf16(af, bh, acc[etl], 0, 0, 0);
            acc[etl] = __builtin_amdgcn_mfma_f32_16x16x32_bf16(af, bl, acc[etl], 0, 0, 0);
        }
    }

    // epilogue: C col=(l&15) within et-tile, row=(l>>4)*4+rr -> n'=h*512+(it0+(l>>4))*4+rr
    #pragma unroll
    for (int etl = 0; etl < 8; ++etl) {
        int e = (eh * 8 + etl) * 16 + (l & 15);
        float bias = bo[e];
        #pragma unroll
        for (int rr = 0; rr < 4; ++rr) {
            int nprime = h * 512 + (it0 + (l >> 4)) * 4 + rr;
            out[((size_t)b * N + nprime) * E + e] = acc[etl][rr] + bias;
        }
    }
}

extern "C" void kernel_launch(void* const* d_in, const int* in_sizes, int n_in,
                              void* d_out, int out_size, void* d_ws, size_t ws_size,
                              hipStream_t stream) {
    const float* X  = (const float*)d_in[0];
    const int*   A  = (const int*)d_in[1];
    const float* W  = (const float*)d_in[2];
    const float* a  = (const float*)d_in[3];
    const float* Wo = (const float*)d_in[4];
    const float* bo = (const float*)d_in[5];
    float* out = (float*)d_out;

    // ws: 4 partials (16.8MB), HpF (4.2MB), H1 (128KB), H2i (128KB), Abits (2MB), WoF (256KB)
    unsigned short* wsu  = (unsigned short*)d_ws;
    unsigned short* part = wsu;
    unsigned short* HpF  = wsu + (size_t)JQ * B * 128 * CH;
    float* H1  = (float*)(HpF + (size_t)B * H * D * N);
    float* H2i = H1 + B * H * N;
    unsigned int* Abits = (unsigned int*)(H2i + (size_t)B * N * H);
    unsigned short* WoF = (unsigned short*)(Abits + (size_t)B * 64 * 2048);

    k_pack<<<dim3(B * N / 4), dim3(256), 0, stream>>>(A, Abits);
    k_wof<<<dim3(32), dim3(256), 0, stream>>>(Wo, WoF);
    k_proj<<<dim3(B * N / NT), dim3(256), 0, stream>>>(X, W, a, HpF, H1, H2i);
    k_agg<<<dim3(JQ * B * 128), dim3(256), 0, stream>>>(Abits, H1, H2i, HpF, part);
    k_out<<<dim3(B * 32 * 2), dim3(256), 0, stream>>>(part, WoF, bo, out);
}

// Round 11
// 142.261 us; speedup vs baseline: 1.0951x; 1.0951x over previous
//
#include <hip/hip_runtime.h>

// Problem constants (fixed by setup_inputs)
constexpr int B = 4, N = 2048, I = 256, H = 4, D = 64, E = 256; // E = H*D
constexpr float LOG2E = 1.44269504088896340736f;

typedef __bf16 bf16x8 __attribute__((ext_vector_type(8)));
typedef float f32x4 __attribute__((ext_vector_type(4)));
typedef unsigned short us8 __attribute__((ext_vector_type(8)));

__device__ __forceinline__ unsigned short f2bf(float f) {
    unsigned u = __builtin_bit_cast(unsigned, f);
    u = (u + 0x7FFFu + ((u >> 16) & 1u)) >> 16;  // RNE
    return (unsigned short)u;
}
__device__ __forceinline__ float bf2f(unsigned short s) {
    return __builtin_bit_cast(float, (unsigned)s << 16);
}

constexpr int NT = 8;   // nodes per proj block
constexpr int CH = 4096; // u16 per (jh,b,it) chunk: 64 q-slots x 64 lanes

// ---------------- Kernel 1 (fused prep): proj | pack | wof by block range ----------------
// proj blocks [0,1024): Hp projection + H1/H2i (log2-scaled) + HpF (B-fragment order)
// pack blocks [1024,3072): adjacency -> bitmask Abits[b][j/32][i]
// wof  blocks [3072,3104): Wo -> bf16 hi/lo B-fragment order
__global__ __launch_bounds__(256) void k_prep(const float* __restrict__ X,
                                              const int* __restrict__ A,
                                              const float* __restrict__ W,
                                              const float* __restrict__ a,
                                              const float* __restrict__ Wo,
                                              unsigned short* __restrict__ HpF,
                                              float* __restrict__ H1,
                                              float* __restrict__ H2i,
                                              unsigned int* __restrict__ Abits,
                                              unsigned short* __restrict__ WoF) {
    int bid = blockIdx.x;
    int t = threadIdx.x;

    if (bid < B * N / NT) {
        // ---------------- projection ----------------
        int b = bid / (N / NT);
        int n0 = (bid % (N / NT)) * NT;
        int h = t >> 6, d = t & 63;

        __shared__ float Xs[NT][I]; // 8 KB

        const float4* Xr = (const float4*)(X + ((size_t)b * N + n0) * I);
        #pragma unroll
        for (int k = 0; k < (NT * I / 4) / 256; ++k) { // 2 iters
            int v = t + 256 * k;
            ((float4*)&Xs[0][0])[v] = Xr[v];
        }
        __syncthreads();

        float acc[NT];
        #pragma unroll
        for (int nn = 0; nn < NT; ++nn) acc[nn] = 0.f;

        const float* Wp = W + (size_t)h * I * D + d;
        #pragma unroll 2
        for (int i4 = 0; i4 < I; i4 += 4) {
            float w0 = Wp[(size_t)(i4 + 0) * D];
            float w1 = Wp[(size_t)(i4 + 1) * D];
            float w2 = Wp[(size_t)(i4 + 2) * D];
            float w3 = Wp[(size_t)(i4 + 3) * D];
            #pragma unroll
            for (int nn = 0; nn < NT; ++nn) {
                float4 x = *(const float4*)&Xs[nn][i4];
                acc[nn] += x.x * w0 + x.y * w1 + x.z * w2 + x.w * w3;
            }
        }

        float a1 = a[h * (2 * D) + d];
        float a2 = a[h * (2 * D) + D + d];

        #pragma unroll
        for (int nn = 0; nn < NT; ++nn) {
            float v1 = acc[nn] * a1;
            float v2 = acc[nn] * a2;
            #pragma unroll
            for (int off = 32; off > 0; off >>= 1) {
                v1 += __shfl_down(v1, off, 64);
                v2 += __shfl_down(v2, off, 64);
            }
            if (d == 0) {
                H1[(size_t)(b * H + h) * N + (n0 + nn)] = v1 * LOG2E;
                H2i[((size_t)b * N + n0 + nn) * H + h] = v2 * LOG2E;
            }
        }

        us8 o;
        #pragma unroll
        for (int nn = 0; nn < NT; ++nn) o[nn] = f2bf(acc[nn]);
        int jblk = n0 >> 5, g = (n0 >> 3) & 3;
        int lane = (d & 15) + 16 * g, ntt = d >> 4;
        ((us8*)HpF)[(((size_t)(b * H + h) * 64 + jblk) * 4 + ntt) * 64 + lane] = o;

    } else if (bid < B * N / NT + B * N / 4) {
        // ---------------- adjacency pack ----------------
        int blk = bid - B * N / NT;
        int w = blk * 4 + (t >> 6); // row id = b*N + i
        int l = t & 63;
        int b = w >> 11;
        int i = w & 2047;
        const int* Arow = A + (size_t)w * N;
        unsigned int* dst = Abits + (size_t)b * 64 * 2048 + i;
        #pragma unroll 4
        for (int it = 0; it < N / 64; ++it) { // 32
            int av = Arow[it * 64 + l];
            unsigned long long m = __ballot(av > 0);
            if (l == 0) {
                dst[(size_t)(it * 2) * 2048]     = (unsigned int)m;
                dst[(size_t)(it * 2 + 1) * 2048] = (unsigned int)(m >> 32);
            }
        }
    } else {
        // ---------------- Wo fragment conversion ----------------
        int gid = (bid - (B * N / NT + B * N / 4)) * 256 + t;  // 8192
        int l = gid & 63, ks = (gid >> 6) & 7, et = gid >> 9;
        int row = et * 16 + (l & 15);
        int col = ks * 32 + (l >> 4) * 8;
        const float* src = Wo + (size_t)row * E + col;
        us8 hi, lo;
        #pragma unroll
        for (int e = 0; e < 8; ++e) {
            float v = src[e];
            unsigned short hb = f2bf(v);
            hi[e] = hb;
            lo[e] = f2bf(v - bf2f(hb));
        }
        ((us8*)WoF)[gid] = hi;
        ((us8*)WoF)[8192 + gid] = lo;
    }
}

// ---------------- Kernel 2: barrier-free per-wave head-softmax + MFMA aggregation ----------------
// 1024 blocks x 4 waves. XCD-locality swizzle: bid&7 = (jh<<2)|b -> with round-robin
// block->XCD dispatch, each XCD touches only HpF(b) (1MB) + Abits(b,jh) + H2i(b):
// L2-resident working set (~1.6MB < 4MB/XCD) so Hf/H2 loads are L2 hits.
// Wave wv covers j in [jh*1024 + wv*256, +256), 8 steps of 32 j. Lane l owns A-frag
// slots (row=l&15, k=(l>>4)*8+e); 4-head softmax once per pair in regs; B-frags =
// coalesced 1KB loads from HpF. End-of-kernel 4-wave LDS reduce -> bf16 chunk.
constexpr int JRANGE = 256;
constexpr int NSTEP = JRANGE / 32;  // 8

__global__ __launch_bounds__(256) void k_agg(const unsigned int* __restrict__ Abits,
                                             const float* __restrict__ H1,
                                             const float* __restrict__ H2i,
                                             const unsigned short* __restrict__ HpF,
                                             unsigned short* __restrict__ part) {
    __shared__ unsigned short red[4][CH]; // 32 KB

    int bid = blockIdx.x;
    int b  = bid & 3;            // low bits -> XCD-locality
    int jh = (bid >> 2) & 1;
    int it = bid >> 3;
    int t = threadIdx.x;
    int wv = t >> 6, l = t & 63;
    int i0 = it * 16;
    int jb = jh * 1024 + wv * JRANGE;
    int jt0 = jb >> 5;           // first 32-j tile index
    int row = l & 15;  // A-frag row / B-frag col
    int kg  = l >> 4;  // k-chunk: k = kg*8 + e

    float h1v[H];
    #pragma unroll
    for (int h = 0; h < H; ++h) h1v[h] = H1[(size_t)(b * H + h) * N + i0 + row];

    f32x4 acc[H][4] = {}; // [head][d-tile]

    const unsigned int* Abp = Abits + (size_t)b * 64 * 2048 + i0 + row; // + jt*2048
    const float4* H2r = (const float4*)(H2i + ((size_t)b * N + jb + kg * 8) * H);
    const us8* Hf = (const us8*)HpF + ((size_t)(b * H) * 64 + jt0) * 256 + l;

    unsigned int aw = Abp[(size_t)jt0 * 2048];

    #pragma unroll 2
    for (int s = 0; s < NSTEP; ++s) {
        int sn = (s + 1 < NSTEP) ? (s + 1) : s;
        unsigned int awn = Abp[(size_t)(jt0 + sn) * 2048];

        // ---- softmax for 8 pairs, all 4 heads; bit-test mask, one float4 H2/pair ----
        bf16x8 af[H];
        #pragma unroll
        for (int e = 0; e < 8; ++e) {
            bool on = (aw >> (kg * 8 + e)) & 1u;
            float4 h2 = H2r[s * 32 + e]; // heads 0..3 of pair j = jb+kg*8+s*32+e
            float v0 = h1v[0] + h2.x;
            float v1 = h1v[1] + h2.y;
            float v2 = h1v[2] + h2.z;
            float v3 = h1v[3] + h2.w;
            // leaky-relu in log2 domain; mask score to 0 (exp2(0)=1 -> w=0.25 exact)
            float s0 = on ? fmaxf(v0, 0.2f * v0) : 0.f;
            float s1 = on ? fmaxf(v1, 0.2f * v1) : 0.f;
            float s2 = on ? fmaxf(v2, 0.2f * v2) : 0.f;
            float s3 = on ? fmaxf(v3, 0.2f * v3) : 0.f;
            float e0 = exp2f(s0);
            float e1 = exp2f(s1);
            float e2 = exp2f(s2);
            float e3 = exp2f(s3);
            float zi = __builtin_amdgcn_rcpf(e0 + e1 + e2 + e3);
            af[0][e] = (__bf16)(e0 * zi);
            af[1][e] = (__bf16)(e1 * zi);
            af[2][e] = (__bf16)(e2 * zi);
            af[3][e] = (__bf16)(e3 * zi);
        }

        // ---- MFMA: 4 heads x 4 d-tiles; B-frag = coalesced 1KB load ----
        #pragma unroll
        for (int h = 0; h < H; ++h) {
            #pragma unroll
            for (int nt = 0; nt < 4; ++nt) {
                bf16x8 bfr = __builtin_bit_cast(bf16x8, Hf[(size_t)h * 64 * 256 + s * 256 + nt * 64]);
                acc[h][nt] = __builtin_amdgcn_mfma_f32_16x16x32_bf16(af[h], bfr, acc[h][nt], 0, 0, 0);
            }
        }

        aw = awn;
    }

    // ---- end-of-kernel reduce: each wave dumps bf16 to its LDS slot; sum 4 slots ----
    #pragma unroll
    for (int h = 0; h < H; ++h)
        #pragma unroll
        for (int nt = 0; nt < 4; ++nt)
            #pragma unroll
            for (int r = 0; r < 4; ++r)
                red[wv][(((h * 4 + nt) * 4 + r)) * 64 + l] = f2bf(acc[h][nt][r]);
    __syncthreads();

    unsigned short* chunk = part + (((size_t)jh * B + b) * 128 + it) * CH;
    #pragma unroll
    for (int k = 0; k < CH / 256; ++k) { // 16
        int idx = t + 256 * k;
        float s = bf2f(red[0][idx]) + bf2f(red[1][idx]) + bf2f(red[2][idx]) + bf2f(red[3][idx]);
        chunk[idx] = f2bf(s);
    }
}

// ---------------- Kernel 3: MFMA out-GEMM, no LDS, no barriers ----------------
// Chunk layout: for (n' = h*512 + it*4 + kg, k = r*64 + nt*16 + rw):
//   chunk(jh,b,it)[ ((h*4+nt)*4+r)*64 + kg*16 + rw ]
// A-frag (row m=l&15 -> it=it0+(m>>2), kg=m&3; k=ks*32+(l>>4)*8+e) = contiguous us8.
// B-frag from WoF (hi+lo pair, 2 MFMAs -> Wo exact to fp32).
__global__ __launch_bounds__(256) void k_out(const unsigned short* __restrict__ part,
                                             const unsigned short* __restrict__ WoF,
                                             const float* __restrict__ bo,
                                             float* __restrict__ out) {
    int bid = blockIdx.x;           // ((b*32)+itg)*2 + eh
    int eh  = bid & 1;
    int itg = (bid >> 1) & 31;
    int b   = bid >> 6;
    int t = threadIdx.x;
    int h = t >> 6, l = t & 63;
    int it0 = itg * 4;
    int m = l & 15;                 // A-row within 16-row tile
    int it = it0 + (m >> 2), kg = m & 3;
    int kh = l >> 4;

    const unsigned short* c0 = part + ((size_t)(0 * B + b) * 128 + it) * CH;
    const unsigned short* c1 = part + ((size_t)(1 * B + b) * 128 + it) * CH;
    const us8* wf = (const us8*)WoF;

    f32x4 acc[8] = {};

    #pragma unroll
    for (int ks = 0; ks < 8; ++ks) {
        int k0 = ks * 32 + kh * 8;
        int nt = (k0 >> 4) & 3, r = k0 >> 6, rw0 = k0 & 15;
        int cidx = ((h * 4 + nt) * 4 + r) * 64 + kg * 16 + rw0;
        us8 p0 = *(const us8*)(c0 + cidx);
        us8 p1 = *(const us8*)(c1 + cidx);
        bf16x8 af;
        #pragma unroll
        for (int e = 0; e < 8; ++e) af[e] = (__bf16)(bf2f(p0[e]) + bf2f(p1[e]));

        #pragma unroll
        for (int etl = 0; etl < 8; ++etl) {
            int et = eh * 8 + etl;
            bf16x8 bh = __builtin_bit_cast(bf16x8, wf[(size_t)(et * 8 + ks) * 64 + l]);
            bf16x8 bl = __builtin_bit_cast(bf16x8, wf[8192 + (size_t)(et * 8 + ks) * 64 + l]);
            acc[etl] = __builtin_amdgcn_mfma_f32_16x16x32_bf16(af, bh, acc[etl], 0, 0, 0);
            acc[etl] = __builtin_amdgcn_mfma_f32_16x16x32_bf16(af, bl, acc[etl], 0, 0, 0);
        }
    }

    // epilogue: C col=(l&15) within et-tile, row=(l>>4)*4+rr -> n'=h*512+(it0+(l>>4))*4+rr
    #pragma unroll
    for (int etl = 0; etl < 8; ++etl) {
        int e = (eh * 8 + etl) * 16 + (l & 15);
        float bias = bo[e];
        #pragma unroll
        for (int rr = 0; rr < 4; ++rr) {
            int nprime = h * 512 + (it0 + (l >> 4)) * 4 + rr;
            out[((size_t)b * N + nprime) * E + e] = acc[etl][rr] + bias;
        }
    }
}

extern "C" void kernel_launch(void* const* d_in, const int* in_sizes, int n_in,
                              void* d_out, int out_size, void* d_ws, size_t ws_size,
                              hipStream_t stream) {
    const float* X  = (const float*)d_in[0];
    const int*   A  = (const int*)d_in[1];
    const float* W  = (const float*)d_in[2];
    const float* a  = (const float*)d_in[3];
    const float* Wo = (const float*)d_in[4];
    const float* bo = (const float*)d_in[5];
    float* out = (float*)d_out;

    // ws: 2 partials (8.4MB), HpF (4.2MB), H1 (128KB), H2i (128KB), Abits (2MB), WoF (256KB)
    unsigned short* wsu  = (unsigned short*)d_ws;
    unsigned short* part = wsu;
    unsigned short* HpF  = wsu + (size_t)2 * B * 128 * CH;
    float* H1  = (float*)(HpF + (size_t)B * H * D * N);
    float* H2i = H1 + B * H * N;
    unsigned int* Abits = (unsigned int*)(H2i + (size_t)B * N * H);
    unsigned short* WoF = (unsigned short*)(Abits + (size_t)B * 64 * 2048);

    k_prep<<<dim3(B * N / NT + B * N / 4 + 32), dim3(256), 0, stream>>>(
        X, A, W, a, Wo, HpF, H1, H2i, Abits, WoF);
    k_agg<<<dim3(2 * B * 128), dim3(256), 0, stream>>>(Abits, H1, H2i, HpF, part);
    k_out<<<dim3(B * 32 * 2), dim3(256), 0, stream>>>(part, WoF, bo, out);
}